// Round 15
// baseline (1111.780 us; speedup 1.0000x reference)
//
#include <hip/hip_runtime.h>
#include <hip/hip_bf16.h>

#define B_ 4
#define N_ 4096
#define NS_ 1024
#define KNN_ 32
#define NPOS_ 131072   /* B_*NS_*KNN_ */
#define BN_EPS_ 1e-5f

using bf16 = __hip_bfloat16;
typedef unsigned short us;
typedef __attribute__((ext_vector_type(8))) short short8;
typedef __attribute__((ext_vector_type(4))) float f32x4;
typedef unsigned long long ull;

__device__ __forceinline__ float bf2f(bf16 h){ return __bfloat162float(h); }
__device__ __forceinline__ us f2bfbits(float x){
    bf16 h = __float2bfloat16(x);
    return *reinterpret_cast<us*>(&h);
}
__device__ __forceinline__ float bits2f(us u){
    unsigned v = ((unsigned)u)<<16; return __uint_as_float(v);
}
__device__ __forceinline__ void unpack8(uint4 v, float* f){
    f[0]=__uint_as_float((v.x&0xFFFFu)<<16); f[1]=__uint_as_float(v.x&0xFFFF0000u);
    f[2]=__uint_as_float((v.y&0xFFFFu)<<16); f[3]=__uint_as_float(v.y&0xFFFF0000u);
    f[4]=__uint_as_float((v.z&0xFFFFu)<<16); f[5]=__uint_as_float(v.z&0xFFFF0000u);
    f[6]=__uint_as_float((v.w&0xFFFFu)<<16); f[7]=__uint_as_float(v.w&0xFFFF0000u);
}
__device__ __forceinline__ uint4 pack8(const float* f){
    uint4 v;
    v.x = (unsigned)f2bfbits(f[0]) | ((unsigned)f2bfbits(f[1])<<16);
    v.y = (unsigned)f2bfbits(f[2]) | ((unsigned)f2bfbits(f[3])<<16);
    v.z = (unsigned)f2bfbits(f[4]) | ((unsigned)f2bfbits(f[5])<<16);
    v.w = (unsigned)f2bfbits(f[6]) | ((unsigned)f2bfbits(f[7])<<16);
    return v;
}
__device__ __forceinline__ unsigned fmono(float v){
    unsigned u = __float_as_uint(v);
    return (u & 0x80000000u) ? ~u : (u | 0x80000000u);
}

// ---- DPP wave64 reductions ----
template<int CTRL, int ROWM>
__device__ __forceinline__ float dppmaxf(float x){
    int xi = __float_as_int(x);
    int yi = __builtin_amdgcn_update_dpp(xi, xi, CTRL, ROWM, 0xF, false);
    return fmaxf(x, __int_as_float(yi));
}
template<int CTRL, int ROWM>
__device__ __forceinline__ float dppminf(float x){
    int xi = __float_as_int(x);
    int yi = __builtin_amdgcn_update_dpp(xi, xi, CTRL, ROWM, 0xF, false);
    return fminf(x, __int_as_float(yi));
}
__device__ __forceinline__ float wave_max_f32(float x){
    x = dppmaxf<0x111,0xF>(x);
    x = dppmaxf<0x112,0xF>(x);
    x = dppmaxf<0x114,0xF>(x);
    x = dppmaxf<0x118,0xF>(x);
    x = dppmaxf<0x142,0xA>(x);
    x = dppmaxf<0x143,0xC>(x);
    return __int_as_float(__builtin_amdgcn_readlane(__float_as_int(x), 63));
}
__device__ __forceinline__ float wave_min_f32(float x){
    x = dppminf<0x111,0xF>(x);
    x = dppminf<0x112,0xF>(x);
    x = dppminf<0x114,0xF>(x);
    x = dppminf<0x118,0xF>(x);
    x = dppminf<0x142,0xA>(x);
    x = dppminf<0x143,0xC>(x);
    return __int_as_float(__builtin_amdgcn_readlane(__float_as_int(x), 63));
}
// sum across each 16-lane DPP row; lane (lane&15)==15 holds row total
__device__ __forceinline__ float rowsum16(float x){
    x += __int_as_float(__builtin_amdgcn_update_dpp(0, __float_as_int(x), 0x111, 0xF, 0xF, true));
    x += __int_as_float(__builtin_amdgcn_update_dpp(0, __float_as_int(x), 0x112, 0xF, 0xF, true));
    x += __int_as_float(__builtin_amdgcn_update_dpp(0, __float_as_int(x), 0x114, 0xF, 0xF, true));
    x += __int_as_float(__builtin_amdgcn_update_dpp(0, __float_as_int(x), 0x118, 0xF, 0xF, true));
    return x;
}
// full 64-lane sum -> all lanes get it via readlane 63
__device__ __forceinline__ float wave_sum_f32(float x){
    x = rowsum16(x);
    x += __int_as_float(__builtin_amdgcn_update_dpp(0, __float_as_int(x), 0x142, 0xA, 0xF, false));
    x += __int_as_float(__builtin_amdgcn_update_dpp(0, __float_as_int(x), 0x143, 0xC, 0xF, false));
    return __int_as_float(__builtin_amdgcn_readlane(__float_as_int(x), 63));
}
__device__ __forceinline__ float max16(const float* v){
    float a = fmaxf(fmaxf(fmaxf(v[0],v[1]),v[2]),v[3]);
    float b = fmaxf(fmaxf(fmaxf(v[4],v[5]),v[6]),v[7]);
    float c = fmaxf(fmaxf(fmaxf(v[8],v[9]),v[10]),v[11]);
    float d = fmaxf(fmaxf(fmaxf(v[12],v[13]),v[14]),v[15]);
    return fmaxf(fmaxf(a,b), fmaxf(c,d));
}
__device__ __forceinline__ float min16(const float* v){
    float a = fminf(fminf(fminf(v[0],v[1]),v[2]),v[3]);
    float b = fminf(fminf(fminf(v[4],v[5]),v[6]),v[7]);
    float c = fminf(fminf(fminf(v[8],v[9]),v[10]),v[11]);
    float d = fminf(fminf(fminf(v[12],v[13]),v[14]),v[15]);
    return fminf(fminf(a,b), fminf(c,d));
}

// Partial-stats layout: part[(ch*2+k)*64 + slot], ch in [0,1024)
#define NSLOT 64

// -------------------- BN coef from 64-slot partials (bn3 only) ---------------
__global__ __launch_bounds__(256) void bn_coef(const float* __restrict__ part,
                                               const float* __restrict__ g,
                                               const float* __restrict__ be,
                                               int chbase, int C,
                                               float2* __restrict__ ab){
    int c = blockIdx.x*256 + threadIdx.x;
    if (c < C){
        const float* ps = part + (size_t)(chbase+c)*2*NSLOT;
        float s = 0.f, q = 0.f;
        #pragma unroll 8
        for (int i=0;i<NSLOT;i++){ s += ps[i]; q += ps[NSLOT+i]; }
        const float inv = 1.0f/(float)NPOS_;
        float mean = s*inv;
        float var  = q*inv - mean*mean;
        float a = g[c]*rsqrtf(var + BN_EPS_);
        ab[c] = make_float2(a, be[c] - mean*a);
    }
}

// -------------------- mega: FPS producer + preps + convknn consumers ----------
__global__ __launch_bounds__(256) void mega_kernel(const float* __restrict__ p,
                                                   const float* __restrict__ f,
                                                   float* __restrict__ cntrd,
                                                   float* __restrict__ part,
                                                   int* __restrict__ prog,
                                                   int* __restrict__ w26flag,
                                                   const float* __restrict__ w1,
                                                   const float* __restrict__ w2,
                                                   float* __restrict__ W26,
                                                   const float* __restrict__ b2,
                                                   const float* __restrict__ w3,
                                                   us* __restrict__ whi3,
                                                   const float* __restrict__ w4,
                                                   us* __restrict__ whi4,
                                                   bf16* __restrict__ z2){
    __shared__ float4 pxyz[N_];
    __shared__ ull warr[2][4];
    __shared__ int knnS[32];
    __shared__ float Ws[6][256];
    __shared__ float xs[6][32];
    __shared__ int ciS;
    const int bid = blockIdx.x;
    const int t = threadIdx.x;
    const int lane = t & 63;
    const int wave = t >> 6;

    if (bid < 4){
        // ---------------- FPS producer (proven R8/R10 body) ----------------
        const int b = bid;
        const float* pb = p + (size_t)b*N_*3;
        float rx[16], ry[16], rz[16], dist[16];
        #pragma unroll
        for (int j=0;j<16;j++){
            int i = t*16+j;
            float x = pb[i*3+0];
            float y = pb[i*3+1];
            float z = pb[i*3+2];
            rx[j]=x; ry[j]=y; rz[j]=z;
            pxyz[i] = make_float4(x,y,z,0.f);
            dist[j]=1e10f;
        }
        __syncthreads();
        float4 c = pxyz[0];
        if (t==0){
            atomicExch(&prog[b*NS_], 1);
            cntrd[(size_t)(b*NS_)*3+0] = c.x;
            cntrd[(size_t)(b*NS_)*3+1] = c.y;
            cntrd[(size_t)(b*NS_)*3+2] = c.z;
        }
        for (int s=1; s<NS_; s++){
            #pragma unroll
            for (int j=0;j<16;j++){
                float dx = __fsub_rn(rx[j],c.x);
                float dy = __fsub_rn(ry[j],c.y);
                float dz = __fsub_rn(rz[j],c.z);
                float d  = __fadd_rn(__fadd_rn(__fmul_rn(dx,dx),__fmul_rn(dy,dy)),__fmul_rn(dz,dz));
                dist[j] = fminf(dist[j], d);
            }
            float lmax = max16(dist);
            float wmax = wave_max_f32(lmax);
            unsigned msk = 0;
            #pragma unroll
            for (int j=0;j<16;j++) msk |= (dist[j]==wmax) ? (1u<<j) : 0u;
            ull ball = __ballot(msk != 0);
            int srclane = (int)__builtin_ctzll(ball);
            unsigned lmsk = (unsigned)__builtin_amdgcn_readlane((int)msk, srclane);
            int widx = (wave*64 + srclane)*16 + (int)__builtin_ctz(lmsk);
            if (lane==0)
                warr[s&1][wave] = ((ull)__float_as_uint(wmax)<<32) | (0xFFFFFFFFu - (unsigned)widx);
            __syncthreads();
            ull g0 = warr[s&1][0], g1 = warr[s&1][1], g2 = warr[s&1][2], g3 = warr[s&1][3];
            ull ga = g0 > g1 ? g0 : g1;
            ull gb = g2 > g3 ? g2 : g3;
            ull g  = ga > gb ? ga : gb;
            int cur = (int)(0xFFFFFFFFu - (unsigned)(g & 0xFFFFFFFFull));
            c = pxyz[cur];
            if (t==0){
                atomicExch(&prog[b*NS_+s], cur+1);
                cntrd[(size_t)(b*NS_+s)*3+0] = c.x;
                cntrd[(size_t)(b*NS_+s)*3+1] = c.y;
                cntrd[(size_t)(b*NS_+s)*3+2] = c.z;
            }
        }
        return;
    }
    if (bid == 4){
        float acc[6] = {0,0,0,0,0,0};
        for (int k=0;k<256;k++){
            float w2v = w2[t*256+k];
            #pragma unroll
            for (int j=0;j<6;j++) acc[j] = fmaf(w2v, w1[k*6+j], acc[j]);
        }
        #pragma unroll
        for (int j=0;j<6;j++) W26[j*256+t] = acc[j];
        __syncthreads();
        if (t==0){ __threadfence(); atomicExch(w26flag, 1); }
        return;
    }
    if (bid < 1029){              // cast w3 -> bf16
        int i = (bid-5)*256 + t;
        whi3[i] = f2bfbits(w3[i]);
        return;
    }
    if (bid < 1541){              // cast w4 -> bf16
        int i = (bid-1029)*256 + t;
        whi4[i] = f2bfbits(w4[i]);
        return;
    }
    // ---------------- convknn worker ----------------
    const int wid = bid - 1541;
    const int b = wid & 3;
    const int si = wid >> 2;
    const int sidx = b*NS_ + si;
    const float* pb = p + (size_t)b*N_*3;
    if (t == 0){
        int v;
        while ((v = atomicAdd(&prog[sidx], 0)) == 0) {}
        ciS = v - 1;
    }
    __syncthreads();
    const int ci = ciS;
    float cx = pb[ci*3+0];
    float cy = pb[ci*3+1];
    float cz = pb[ci*3+2];
    float c2 = __fadd_rn(__fadd_rn(__fmul_rn(cx,cx),__fmul_rn(cy,cy)),__fmul_rn(cz,cz));
    float d2[16];
    #pragma unroll
    for (int j=0;j<16;j++){
        int i = t*16+j;
        float x = pb[i*3+0];
        float y = pb[i*3+1];
        float z = pb[i*3+2];
        float p2 = __fadd_rn(__fadd_rn(__fmul_rn(x,x),__fmul_rn(y,y)),__fmul_rn(z,z));
        float dot= __fadd_rn(__fadd_rn(__fmul_rn(cx,x),__fmul_rn(cy,y)),__fmul_rn(cz,z));
        d2[j] = __fsub_rn(__fadd_rn(c2,p2), __fmul_rn(2.0f,dot));
    }
    for (int it=0; it<KNN_; it++){
        float lmin = min16(d2);
        float wmin = wave_min_f32(lmin);
        unsigned msk = 0;
        #pragma unroll
        for (int j=0;j<16;j++) msk |= (d2[j]==wmin) ? (1u<<j) : 0u;
        ull ball = __ballot(msk != 0);
        int srclane = (int)__builtin_ctzll(ball);
        unsigned lmsk = (unsigned)__builtin_amdgcn_readlane((int)msk, srclane);
        int widx = (wave*64 + srclane)*16 + (int)__builtin_ctz(lmsk);
        if (lane==0)
            warr[it&1][wave] = ((ull)fmono(wmin)<<32) | (unsigned)widx;
        __syncthreads();
        ull g0 = warr[it&1][0], g1 = warr[it&1][1], g2 = warr[it&1][2], g3 = warr[it&1][3];
        ull ga = g0 < g1 ? g0 : g1;
        ull gb = g2 < g3 ? g2 : g3;
        ull g  = ga < gb ? ga : gb;
        int idx = (int)(g & 0xFFFFFFFFull);
        if ((idx>>4)==t) d2[idx & 15] = INFINITY;
        if (t==0) knnS[it] = idx;
    }
    if (t == 0){ while (atomicAdd(w26flag, 0) == 0) {} __threadfence(); }
    __syncthreads();
    #pragma unroll
    for (int r=0;r<6;r++) Ws[r][t] = W26[r*256+t];
    if (t < 32){
        int i = knnS[t];
        const float* fb = f + (size_t)b*3*N_;
        xs[0][t] = pb[i*3+0];
        xs[1][t] = pb[i*3+1];
        xs[2][t] = pb[i*3+2];
        xs[3][t] = fb[0*N_+i];
        xs[4][t] = fb[1*N_+i];
        xs[5][t] = fb[2*N_+i];
    }
    __syncthreads();
    float w0=Ws[0][t], w1v=Ws[1][t], w2v=Ws[2][t], w3v=Ws[3][t], w4v=Ws[4][t], w5v=Ws[5][t];
    float bias = b2[t];
    bf16* zrow = z2 + (size_t)t*NPOS_ + (size_t)sidx*KNN_;
    float ssum = 0.f, sq = 0.f;
    for (int k0=0;k0<32;k0+=8){
        float y[8];
        #pragma unroll
        for (int u=0;u<8;u++){
            int k = k0+u;
            float acc = bias;
            acc = fmaf(w0, xs[0][k], acc);
            acc = fmaf(w1v,xs[1][k], acc);
            acc = fmaf(w2v,xs[2][k], acc);
            acc = fmaf(w3v,xs[3][k], acc);
            acc = fmaf(w4v,xs[4][k], acc);
            acc = fmaf(w5v,xs[5][k], acc);
            float vr = bits2f(f2bfbits(acc));
            ssum += vr; sq = fmaf(vr, vr, sq);
            y[u] = acc;
        }
        *reinterpret_cast<uint4*>(zrow + k0) = pack8(y);
    }
    const int slot = wid & (NSLOT-1);
    atomicAdd(&part[(size_t)(t*2+0)*NSLOT + slot], ssum);
    atomicAdd(&part[(size_t)(t*2+1)*NSLOT + slot], sq);
}

// ---- xm + IN-PLACE normalize: z2 <- bf16(relu(bn2(z2))); xm = max_k ---------
// Fused bn2-coef: each block re-reduces its channel's 128 partials (DPP sum).
__global__ __launch_bounds__(256) void xm_kernel(bf16* __restrict__ z2,
                                                 const float* __restrict__ part,
                                                 const float* __restrict__ g2,
                                                 const float* __restrict__ be2,
                                                 bf16* __restrict__ xm){
    __shared__ float abS[2];
    const int c = blockIdx.x >> 4;
    const int t = threadIdx.x;
    const int bs = ((blockIdx.x & 15) << 8) | t;
    if (t < 64){
        float s = part[(size_t)(c*2+0)*NSLOT + t];
        float q = part[(size_t)(c*2+1)*NSLOT + t];
        s = wave_sum_f32(s);
        q = wave_sum_f32(q);
        if (t==0){
            const float inv = 1.0f/(float)NPOS_;
            float mean = s*inv;
            float var  = q*inv - mean*mean;
            float a = g2[c]*rsqrtf(var + BN_EPS_);
            abS[0] = a; abS[1] = be2[c] - mean*a;
        }
    }
    __syncthreads();
    const float a = abS[0], bb = abS[1];
    uint4* xp = reinterpret_cast<uint4*>(z2 + (size_t)c*NPOS_ + (size_t)bs*KNN_);
    float m = 0.0f;   // relu floor
    #pragma unroll
    for (int r=0;r<4;r++){
        uint4 v = xp[r];
        float fv[8]; unpack8(v, fv);
        #pragma unroll
        for (int u=0;u<8;u++) fv[u] = fmaxf(fmaf(fv[u], a, bb), 0.0f);
        #pragma unroll
        for (int u=0;u<8;u++) m = fmaxf(m, fv[u]);
        xp[r] = pack8(fv);      // in-place normalized store
    }
    xm[(size_t)c*4096 + bs] = __float2bfloat16(m);
}

// -------------------- small fp32 GEMM (t3 only) --------------------
__global__ __launch_bounds__(256) void gemm128(const float* __restrict__ A, int lda, int aoff,
                                               const bf16* __restrict__ B,
                                               int M, int N, int K,
                                               float* __restrict__ Cf){
    __shared__ float As[16][128];
    __shared__ float Bs[16][128];
    const int tid = threadIdx.x;
    const int tx = tid & 15, ty = tid >> 4;
    const int m0 = blockIdx.y*128, n0 = blockIdx.x*128;
    float acc[8][8];
    #pragma unroll
    for (int i=0;i<8;i++)
        #pragma unroll
        for (int j=0;j<8;j++) acc[i][j]=0.f;
    const int arow = tid >> 1, akg = tid & 1;
    const int bkk = tid >> 4, bng = tid & 15;
    for (int k0=0;k0<K;k0+=16){
        const float* aptr = A + (size_t)(m0+arow)*lda + aoff + k0 + akg*8;
        float4 a0 = *reinterpret_cast<const float4*>(aptr);
        float4 a1 = *reinterpret_cast<const float4*>(aptr+4);
        As[akg*8+0][arow]=a0.x; As[akg*8+1][arow]=a0.y;
        As[akg*8+2][arow]=a0.z; As[akg*8+3][arow]=a0.w;
        As[akg*8+4][arow]=a1.x; As[akg*8+5][arow]=a1.y;
        As[akg*8+6][arow]=a1.z; As[akg*8+7][arow]=a1.w;
        uint4 bv = *reinterpret_cast<const uint4*>(B + (size_t)(k0+bkk)*N + n0 + bng*8);
        float bf[8]; unpack8(bv, bf);
        *reinterpret_cast<float4*>(&Bs[bkk][bng*8+0]) = make_float4(bf[0],bf[1],bf[2],bf[3]);
        *reinterpret_cast<float4*>(&Bs[bkk][bng*8+4]) = make_float4(bf[4],bf[5],bf[6],bf[7]);
        __syncthreads();
        #pragma unroll
        for (int kk=0;kk<16;kk++){
            float a[8], b[8];
            *reinterpret_cast<float4*>(&a[0]) = *reinterpret_cast<float4*>(&As[kk][ty*8+0]);
            *reinterpret_cast<float4*>(&a[4]) = *reinterpret_cast<float4*>(&As[kk][ty*8+4]);
            *reinterpret_cast<float4*>(&b[0]) = *reinterpret_cast<float4*>(&Bs[kk][tx*8+0]);
            *reinterpret_cast<float4*>(&b[4]) = *reinterpret_cast<float4*>(&Bs[kk][tx*8+4]);
            #pragma unroll
            for (int i=0;i<8;i++)
                #pragma unroll
                for (int j=0;j<8;j++)
                    acc[i][j] = fmaf(a[i], b[j], acc[i][j]);
        }
        __syncthreads();
    }
    const int n = n0 + tx*8;
    #pragma unroll
    for (int i=0;i<8;i++){
        int m = m0 + ty*8 + i;
        *reinterpret_cast<float4*>(Cf + (size_t)m*N + n + 0) = make_float4(acc[i][0],acc[i][1],acc[i][2],acc[i][3]);
        *reinterpret_cast<float4*>(Cf + (size_t)m*N + n + 4) = make_float4(acc[i][4],acc[i][5],acc[i][6],acc[i][7]);
    }
}

// -------------------- MFMA GEMM: LDS-staged bf16 A, B copy-or-fused-BN --------
// ab==null: B staged as pure copy (input already normalized, e.g. z2 after xm).
// ab!=null: B staged as relu(ab[k].x*x+ab[k].y) (fused BN).
#define LDK 40
__global__ __launch_bounds__(256) void gemm_mfma(const us* __restrict__ Whi,
                                                 int ldw, int aoff,
                                                 const bf16* __restrict__ act, int K,
                                                 const float2* __restrict__ ab,
                                                 bf16* __restrict__ out,
                                                 const float* __restrict__ t3,
                                                 float* __restrict__ part, int chbase){
    __shared__ __align__(16) us AsH[128*LDK];
    __shared__ __align__(16) us Bs [128*LDK];
    __shared__ float t3s[128][4];
    const us* actu = reinterpret_cast<const us*>(act);
    const int t = threadIdx.x;
    const int m0 = blockIdx.x*128, n0 = blockIdx.y*128;
    const int wave = t>>6, lane = t&63;
    const int wm = wave>>1, wn = wave&1;
    const int q = lane>>4, col = lane&15;

    if (t3 && t < 128){
        const float* src = t3 + (size_t)(m0+t)*4096 + (n0>>5);
        t3s[t][0]=src[0]; t3s[t][1]=src[1]; t3s[t][2]=src[2]; t3s[t][3]=src[3];
    }

    f32x4 acc[4][4];
    #pragma unroll
    for (int i=0;i<4;i++)
        #pragma unroll
        for (int j=0;j<4;j++) acc[i][j] = (f32x4){0.f,0.f,0.f,0.f};

    const int ar = t>>1, ah = t&1;
    const int bn = t&127, bh = t>>7;

    for (int k0=0;k0<K;k0+=32){
        const us* sh = Whi + (size_t)(m0+ar)*ldw + aoff + k0 + ah*16;
        uint4 h0 = *reinterpret_cast<const uint4*>(sh);
        uint4 h1 = *reinterpret_cast<const uint4*>(sh+8);
        *reinterpret_cast<uint4*>(&AsH[ar*LDK + ah*16 + 0]) = h0;
        *reinterpret_cast<uint4*>(&AsH[ar*LDK + ah*16 + 8]) = h1;
        us bvals[16];
        if (ab){
            #pragma unroll
            for (int j=0;j<16;j++){
                int k = k0 + bh*16 + j;
                float x = bits2f(actu[(size_t)k*NPOS_ + n0 + bn]);
                float2 s = ab[k];
                bvals[j] = f2bfbits(fmaxf(fmaf(x, s.x, s.y), 0.0f));
            }
        } else {
            #pragma unroll
            for (int j=0;j<16;j++){
                int k = k0 + bh*16 + j;
                bvals[j] = actu[(size_t)k*NPOS_ + n0 + bn];   // pure copy
            }
        }
        *reinterpret_cast<uint4*>(&Bs[bn*LDK + bh*16 + 0]) = *reinterpret_cast<uint4*>(&bvals[0]);
        *reinterpret_cast<uint4*>(&Bs[bn*LDK + bh*16 + 8]) = *reinterpret_cast<uint4*>(&bvals[8]);
        __syncthreads();
        short8 bf[4], afh[4];
        #pragma unroll
        for (int tn=0;tn<4;tn++)
            bf[tn] = *reinterpret_cast<const short8*>(&Bs[(wn*64+tn*16+col)*LDK + q*8]);
        #pragma unroll
        for (int tm=0;tm<4;tm++)
            afh[tm] = *reinterpret_cast<const short8*>(&AsH[(wm*64+tm*16+col)*LDK + q*8]);
        #pragma unroll
        for (int tm=0;tm<4;tm++)
            #pragma unroll
            for (int tn=0;tn<4;tn++)
                acc[tm][tn] = __builtin_amdgcn_mfma_f32_16x16x32_bf16(afh[tm], bf[tn], acc[tm][tn], 0, 0, 0);
        __syncthreads();
    }
    const int slot = (int)(blockIdx.y & (NSLOT-1));
    #pragma unroll
    for (int tm=0;tm<4;tm++){
        #pragma unroll
        for (int r=0;r<4;r++){
            int m_l = wm*64 + tm*16 + q*4 + r;
            float srow = 0.f, qrow = 0.f;
            #pragma unroll
            for (int tn=0;tn<4;tn++){
                int n_l = wn*64 + tn*16 + col;
                float vv = acc[tm][tn][r];
                if (t3) vv += t3s[m_l][n_l>>5];
                us hb = f2bfbits(vv);
                reinterpret_cast<us*>(out)[(size_t)(m0+m_l)*NPOS_ + n0 + n_l] = hb;
                float vr = bits2f(hb);
                srow += vr; qrow = fmaf(vr, vr, qrow);
            }
            srow = rowsum16(srow);
            qrow = rowsum16(qrow);
            if (col == 15){
                atomicAdd(&part[(size_t)((chbase + m0 + m_l)*2+0)*NSLOT + slot], srow);
                atomicAdd(&part[(size_t)((chbase + m0 + m_l)*2+1)*NSLOT + slot], qrow);
            }
        }
    }
}

// ---- final: fused bn4-coef + BN4 + ReLU + maxpool over K -> out (f32) --------
__global__ __launch_bounds__(256) void final_kernel(const bf16* __restrict__ z4,
                                                    const float* __restrict__ part,
                                                    const float* __restrict__ g4,
                                                    const float* __restrict__ be4,
                                                    float* __restrict__ out){
    __shared__ float abS[2];
    const int t = threadIdx.x;
    const int c = (blockIdx.x >> 2) & 255;
    const int b = blockIdx.x >> 10;
    const int s = ((blockIdx.x & 3) << 8) | t;
    if (t < 64){
        float ss = part[(size_t)((768+c)*2+0)*NSLOT + t];
        float qq = part[(size_t)((768+c)*2+1)*NSLOT + t];
        ss = wave_sum_f32(ss);
        qq = wave_sum_f32(qq);
        if (t==0){
            const float inv = 1.0f/(float)NPOS_;
            float mean = ss*inv;
            float var  = qq*inv - mean*mean;
            float a = g4[c]*rsqrtf(var + BN_EPS_);
            abS[0] = a; abS[1] = be4[c] - mean*a;
        }
    }
    __syncthreads();
    const float a = abS[0], bb = abS[1];
    const int bsi = b*NS_ + s;
    const uint4* zp = reinterpret_cast<const uint4*>(z4 + (size_t)c*NPOS_ + (size_t)bsi*KNN_);
    float m = 0.0f;   // relu floor (relu commutes with max)
    #pragma unroll
    for (int r=0;r<4;r++){
        uint4 v = zp[r];
        float fv[8]; unpack8(v, fv);
        #pragma unroll
        for (int u=0;u<8;u++) m = fmaxf(m, fmaf(fv[u], a, bb));
    }
    out[(size_t)(b*256 + c)*NS_ + s] = m;
}

extern "C" void kernel_launch(void* const* d_in, const int* in_sizes, int n_in,
                              void* d_out, int out_size, void* d_ws, size_t ws_size,
                              hipStream_t stream) {
    const float* p   = (const float*)d_in[0];
    const float* f   = (const float*)d_in[1];
    const float* w1  = (const float*)d_in[2];
    const float* w2  = (const float*)d_in[3];
    const float* b2  = (const float*)d_in[4];
    const float* g2  = (const float*)d_in[5];
    const float* be2 = (const float*)d_in[6];
    const float* w3  = (const float*)d_in[7];
    const float* g3  = (const float*)d_in[8];
    const float* be3 = (const float*)d_in[9];
    const float* w4  = (const float*)d_in[10];
    const float* g4  = (const float*)d_in[11];
    const float* be4 = (const float*)d_in[12];

    // Workspace (~215 MB); z4 aliases z2; z2 normalized IN PLACE by xm_kernel.
    char* ws = (char*)d_ws;
    float*  W26  = (float*)(ws + 540672);        // 6 KB
    float2* ab3  = (float2*)(ws + 557056);       // 4 KB
    us* whi3 = (us*)(ws + 561152);               // 512 KB
    us* whi4 = (us*)(ws + 1609728);              // 256 KB
    float*  t3   = (float*)(ws + 2134016);       // 8 MB
    bf16*   z2   = (bf16*)(ws + 10522624);       // 64 MB (reused as z4)
    bf16*   xm   = (bf16*)(ws + 77631488);       // 2 MB
    bf16*   z3   = (bf16*)(ws + 79728640);       // 128 MB (end 213946368)
    float*  part = (float*)(ws + 213946368);     // 512 KB partial stats
    int*    prog = (int*)(ws + 214470656);       // 16 KB progress words
    int*    w26flag = (int*)(ws + 214487040);    // 4 B
    bf16*   z4   = z2;

    float* out_cntrd = (float*)d_out;
    float* out_feat  = (float*)d_out + (size_t)B_*NS_*3;

    // 0: zero part + prog + w26flag in one capturable memset
    hipMemsetAsync(ws + 213946368, 0, 540676, stream);
    // 1: FPS producer + preps + convknn consumers
    mega_kernel<<<5637, 256, 0, stream>>>(p, f, out_cntrd, part, prog, w26flag,
                                          w1, w2, W26, b2,
                                          w3, whi3, w4, whi4, z2);
    // 2: fused bn2-coef + in-place normalize z2 + xm
    xm_kernel<<<4096, 256, 0, stream>>>(z2, part, g2, be2, xm);
    // 3: t3 = w3[:, :256] @ xm
    gemm128<<<dim3(32,4), 256, 0, stream>>>(w3, 512, 0, xm, 512, 4096, 256, t3);
    // 4: z3 = w3[:, 256:] @ z2n + t3   (B pure copy; + BN3 partial stats)
    gemm_mfma<<<dim3(4,1024), 256, 0, stream>>>(whi3, 512, 256, z2, 256, nullptr, z3, t3, part, 256);
    // 5: BN3 coefficients
    bn_coef<<<2, 256, 0, stream>>>(part, g3, be3, 256, 512, ab3);
    // 6: z4 = w4 @ relu(bn3(z3))   (+ BN4 partial stats; z4 aliases z2)
    gemm_mfma<<<dim3(2,1024), 256, 0, stream>>>(whi4, 512, 0, z3, 512, ab3, z4, nullptr, part, 768);
    // 7: fused bn4-coef + BN4 + ReLU + maxpool -> out
    final_kernel<<<4096, 256, 0, stream>>>(z4, part, g4, be4, out_feat);
}

// Round 16
// 1056.127 us; speedup vs baseline: 1.0527x; 1.0527x over previous
//
#include <hip/hip_runtime.h>
#include <hip/hip_bf16.h>

#define B_ 4
#define N_ 4096
#define NS_ 1024
#define KNN_ 32
#define NPOS_ 131072   /* B_*NS_*KNN_ */
#define BN_EPS_ 1e-5f

using bf16 = __hip_bfloat16;
typedef unsigned short us;
typedef __attribute__((ext_vector_type(8))) short short8;
typedef __attribute__((ext_vector_type(4))) float f32x4;
typedef unsigned long long ull;

__device__ __forceinline__ float bf2f(bf16 h){ return __bfloat162float(h); }
__device__ __forceinline__ us f2bfbits(float x){
    bf16 h = __float2bfloat16(x);
    return *reinterpret_cast<us*>(&h);
}
__device__ __forceinline__ float bits2f(us u){
    unsigned v = ((unsigned)u)<<16; return __uint_as_float(v);
}
__device__ __forceinline__ void unpack8(uint4 v, float* f){
    f[0]=__uint_as_float((v.x&0xFFFFu)<<16); f[1]=__uint_as_float(v.x&0xFFFF0000u);
    f[2]=__uint_as_float((v.y&0xFFFFu)<<16); f[3]=__uint_as_float(v.y&0xFFFF0000u);
    f[4]=__uint_as_float((v.z&0xFFFFu)<<16); f[5]=__uint_as_float(v.z&0xFFFF0000u);
    f[6]=__uint_as_float((v.w&0xFFFFu)<<16); f[7]=__uint_as_float(v.w&0xFFFF0000u);
}
__device__ __forceinline__ uint4 pack8(const float* f){
    uint4 v;
    v.x = (unsigned)f2bfbits(f[0]) | ((unsigned)f2bfbits(f[1])<<16);
    v.y = (unsigned)f2bfbits(f[2]) | ((unsigned)f2bfbits(f[3])<<16);
    v.z = (unsigned)f2bfbits(f[4]) | ((unsigned)f2bfbits(f[5])<<16);
    v.w = (unsigned)f2bfbits(f[6]) | ((unsigned)f2bfbits(f[7])<<16);
    return v;
}
__device__ __forceinline__ unsigned fmono(float v){
    unsigned u = __float_as_uint(v);
    return (u & 0x80000000u) ? ~u : (u | 0x80000000u);
}

// ---- DPP wave64 reductions ----
template<int CTRL, int ROWM>
__device__ __forceinline__ float dppmaxf(float x){
    int xi = __float_as_int(x);
    int yi = __builtin_amdgcn_update_dpp(xi, xi, CTRL, ROWM, 0xF, false);
    return fmaxf(x, __int_as_float(yi));
}
template<int CTRL, int ROWM>
__device__ __forceinline__ float dppminf(float x){
    int xi = __float_as_int(x);
    int yi = __builtin_amdgcn_update_dpp(xi, xi, CTRL, ROWM, 0xF, false);
    return fminf(x, __int_as_float(yi));
}
__device__ __forceinline__ float wave_max_f32(float x){
    x = dppmaxf<0x111,0xF>(x);
    x = dppmaxf<0x112,0xF>(x);
    x = dppmaxf<0x114,0xF>(x);
    x = dppmaxf<0x118,0xF>(x);
    x = dppmaxf<0x142,0xA>(x);
    x = dppmaxf<0x143,0xC>(x);
    return __int_as_float(__builtin_amdgcn_readlane(__float_as_int(x), 63));
}
__device__ __forceinline__ float wave_min_f32(float x){
    x = dppminf<0x111,0xF>(x);
    x = dppminf<0x112,0xF>(x);
    x = dppminf<0x114,0xF>(x);
    x = dppminf<0x118,0xF>(x);
    x = dppminf<0x142,0xA>(x);
    x = dppminf<0x143,0xC>(x);
    return __int_as_float(__builtin_amdgcn_readlane(__float_as_int(x), 63));
}
// sum across each 16-lane DPP row; lane (lane&15)==15 holds row total
__device__ __forceinline__ float rowsum16(float x){
    x += __int_as_float(__builtin_amdgcn_update_dpp(0, __float_as_int(x), 0x111, 0xF, 0xF, true));
    x += __int_as_float(__builtin_amdgcn_update_dpp(0, __float_as_int(x), 0x112, 0xF, 0xF, true));
    x += __int_as_float(__builtin_amdgcn_update_dpp(0, __float_as_int(x), 0x114, 0xF, 0xF, true));
    x += __int_as_float(__builtin_amdgcn_update_dpp(0, __float_as_int(x), 0x118, 0xF, 0xF, true));
    return x;
}
// full 64-lane sum -> broadcast via readlane 63
__device__ __forceinline__ float wave_sum_f32(float x){
    x = rowsum16(x);
    x += __int_as_float(__builtin_amdgcn_update_dpp(0, __float_as_int(x), 0x142, 0xA, 0xF, false));
    x += __int_as_float(__builtin_amdgcn_update_dpp(0, __float_as_int(x), 0x143, 0xC, 0xF, false));
    return __int_as_float(__builtin_amdgcn_readlane(__float_as_int(x), 63));
}
__device__ __forceinline__ float max16(const float* v){
    float a = fmaxf(fmaxf(fmaxf(v[0],v[1]),v[2]),v[3]);
    float b = fmaxf(fmaxf(fmaxf(v[4],v[5]),v[6]),v[7]);
    float c = fmaxf(fmaxf(fmaxf(v[8],v[9]),v[10]),v[11]);
    float d = fmaxf(fmaxf(fmaxf(v[12],v[13]),v[14]),v[15]);
    return fmaxf(fmaxf(a,b), fmaxf(c,d));
}
__device__ __forceinline__ float min16(const float* v){
    float a = fminf(fminf(fminf(v[0],v[1]),v[2]),v[3]);
    float b = fminf(fminf(fminf(v[4],v[5]),v[6]),v[7]);
    float c = fminf(fminf(fminf(v[8],v[9]),v[10]),v[11]);
    float d = fminf(fminf(fminf(v[12],v[13]),v[14]),v[15]);
    return fminf(fminf(a,b), fminf(c,d));
}

// Partial-stats layout: part[(ch*2+k)*64 + slot], ch in [0,1024)
#define NSLOT 64

// -------------------- BN coef from 64-slot partials (bn2, bn3) ---------------
__global__ __launch_bounds__(256) void bn_coef(const float* __restrict__ part,
                                               const float* __restrict__ g,
                                               const float* __restrict__ be,
                                               int chbase, int C,
                                               float2* __restrict__ ab){
    int c = blockIdx.x*256 + threadIdx.x;
    if (c < C){
        const float* ps = part + (size_t)(chbase+c)*2*NSLOT;
        float s = 0.f, q = 0.f;
        #pragma unroll 8
        for (int i=0;i<NSLOT;i++){ s += ps[i]; q += ps[NSLOT+i]; }
        const float inv = 1.0f/(float)NPOS_;
        float mean = s*inv;
        float var  = q*inv - mean*mean;
        float a = g[c]*rsqrtf(var + BN_EPS_);
        ab[c] = make_float2(a, be[c] - mean*a);
    }
}

// -------------------- mega: FPS producer + preps + convknn consumers ----------
__global__ __launch_bounds__(256) void mega_kernel(const float* __restrict__ p,
                                                   const float* __restrict__ f,
                                                   float* __restrict__ cntrd,
                                                   float* __restrict__ part,
                                                   int* __restrict__ prog,
                                                   int* __restrict__ w26flag,
                                                   const float* __restrict__ w1,
                                                   const float* __restrict__ w2,
                                                   float* __restrict__ W26,
                                                   const float* __restrict__ b2,
                                                   const float* __restrict__ w3,
                                                   us* __restrict__ whi3,
                                                   const float* __restrict__ w4,
                                                   us* __restrict__ whi4,
                                                   bf16* __restrict__ z2){
    __shared__ float4 pxyz[N_];
    __shared__ ull warr[2][4];
    __shared__ int knnS[32];
    __shared__ float Ws[6][256];
    __shared__ float xs[6][32];
    __shared__ int ciS;
    const int bid = blockIdx.x;
    const int t = threadIdx.x;
    const int lane = t & 63;
    const int wave = t >> 6;

    if (bid < 4){
        // ---------------- FPS producer (proven R8/R10 body) ----------------
        const int b = bid;
        const float* pb = p + (size_t)b*N_*3;
        float rx[16], ry[16], rz[16], dist[16];
        #pragma unroll
        for (int j=0;j<16;j++){
            int i = t*16+j;
            float x = pb[i*3+0];
            float y = pb[i*3+1];
            float z = pb[i*3+2];
            rx[j]=x; ry[j]=y; rz[j]=z;
            pxyz[i] = make_float4(x,y,z,0.f);
            dist[j]=1e10f;
        }
        __syncthreads();
        float4 c = pxyz[0];
        if (t==0){
            atomicExch(&prog[b*NS_], 1);
            cntrd[(size_t)(b*NS_)*3+0] = c.x;
            cntrd[(size_t)(b*NS_)*3+1] = c.y;
            cntrd[(size_t)(b*NS_)*3+2] = c.z;
        }
        for (int s=1; s<NS_; s++){
            #pragma unroll
            for (int j=0;j<16;j++){
                float dx = __fsub_rn(rx[j],c.x);
                float dy = __fsub_rn(ry[j],c.y);
                float dz = __fsub_rn(rz[j],c.z);
                float d  = __fadd_rn(__fadd_rn(__fmul_rn(dx,dx),__fmul_rn(dy,dy)),__fmul_rn(dz,dz));
                dist[j] = fminf(dist[j], d);
            }
            float lmax = max16(dist);
            float wmax = wave_max_f32(lmax);
            unsigned msk = 0;
            #pragma unroll
            for (int j=0;j<16;j++) msk |= (dist[j]==wmax) ? (1u<<j) : 0u;
            ull ball = __ballot(msk != 0);
            int srclane = (int)__builtin_ctzll(ball);
            unsigned lmsk = (unsigned)__builtin_amdgcn_readlane((int)msk, srclane);
            int widx = (wave*64 + srclane)*16 + (int)__builtin_ctz(lmsk);
            if (lane==0)
                warr[s&1][wave] = ((ull)__float_as_uint(wmax)<<32) | (0xFFFFFFFFu - (unsigned)widx);
            __syncthreads();
            ull g0 = warr[s&1][0], g1 = warr[s&1][1], g2 = warr[s&1][2], g3 = warr[s&1][3];
            ull ga = g0 > g1 ? g0 : g1;
            ull gb = g2 > g3 ? g2 : g3;
            ull g  = ga > gb ? ga : gb;
            int cur = (int)(0xFFFFFFFFu - (unsigned)(g & 0xFFFFFFFFull));
            c = pxyz[cur];
            if (t==0){
                atomicExch(&prog[b*NS_+s], cur+1);
                cntrd[(size_t)(b*NS_+s)*3+0] = c.x;
                cntrd[(size_t)(b*NS_+s)*3+1] = c.y;
                cntrd[(size_t)(b*NS_+s)*3+2] = c.z;
            }
        }
        return;
    }
    if (bid == 4){
        float acc[6] = {0,0,0,0,0,0};
        for (int k=0;k<256;k++){
            float w2v = w2[t*256+k];
            #pragma unroll
            for (int j=0;j<6;j++) acc[j] = fmaf(w2v, w1[k*6+j], acc[j]);
        }
        #pragma unroll
        for (int j=0;j<6;j++) W26[j*256+t] = acc[j];
        __syncthreads();
        if (t==0){ __threadfence(); atomicExch(w26flag, 1); }
        return;
    }
    if (bid < 1029){              // cast w3 -> bf16
        int i = (bid-5)*256 + t;
        whi3[i] = f2bfbits(w3[i]);
        return;
    }
    if (bid < 1541){              // cast w4 -> bf16
        int i = (bid-1029)*256 + t;
        whi4[i] = f2bfbits(w4[i]);
        return;
    }
    // ---------------- convknn worker ----------------
    const int wid = bid - 1541;
    const int b = wid & 3;
    const int si = wid >> 2;
    const int sidx = b*NS_ + si;
    const float* pb = p + (size_t)b*N_*3;
    if (t == 0){
        int v;
        while ((v = atomicAdd(&prog[sidx], 0)) == 0) {}
        ciS = v - 1;
    }
    __syncthreads();
    const int ci = ciS;
    float cx = pb[ci*3+0];
    float cy = pb[ci*3+1];
    float cz = pb[ci*3+2];
    float c2 = __fadd_rn(__fadd_rn(__fmul_rn(cx,cx),__fmul_rn(cy,cy)),__fmul_rn(cz,cz));
    float d2[16];
    #pragma unroll
    for (int j=0;j<16;j++){
        int i = t*16+j;
        float x = pb[i*3+0];
        float y = pb[i*3+1];
        float z = pb[i*3+2];
        float p2 = __fadd_rn(__fadd_rn(__fmul_rn(x,x),__fmul_rn(y,y)),__fmul_rn(z,z));
        float dot= __fadd_rn(__fadd_rn(__fmul_rn(cx,x),__fmul_rn(cy,y)),__fmul_rn(cz,z));
        d2[j] = __fsub_rn(__fadd_rn(c2,p2), __fmul_rn(2.0f,dot));
    }
    for (int it=0; it<KNN_; it++){
        float lmin = min16(d2);
        float wmin = wave_min_f32(lmin);
        unsigned msk = 0;
        #pragma unroll
        for (int j=0;j<16;j++) msk |= (d2[j]==wmin) ? (1u<<j) : 0u;
        ull ball = __ballot(msk != 0);
        int srclane = (int)__builtin_ctzll(ball);
        unsigned lmsk = (unsigned)__builtin_amdgcn_readlane((int)msk, srclane);
        int widx = (wave*64 + srclane)*16 + (int)__builtin_ctz(lmsk);
        if (lane==0)
            warr[it&1][wave] = ((ull)fmono(wmin)<<32) | (unsigned)widx;
        __syncthreads();
        ull g0 = warr[it&1][0], g1 = warr[it&1][1], g2 = warr[it&1][2], g3 = warr[it&1][3];
        ull ga = g0 < g1 ? g0 : g1;
        ull gb = g2 < g3 ? g2 : g3;
        ull g  = ga < gb ? ga : gb;
        int idx = (int)(g & 0xFFFFFFFFull);
        if ((idx>>4)==t) d2[idx & 15] = INFINITY;
        if (t==0) knnS[it] = idx;
    }
    if (t == 0){ while (atomicAdd(w26flag, 0) == 0) {} __threadfence(); }
    __syncthreads();
    #pragma unroll
    for (int r=0;r<6;r++) Ws[r][t] = W26[r*256+t];
    if (t < 32){
        int i = knnS[t];
        const float* fb = f + (size_t)b*3*N_;
        xs[0][t] = pb[i*3+0];
        xs[1][t] = pb[i*3+1];
        xs[2][t] = pb[i*3+2];
        xs[3][t] = fb[0*N_+i];
        xs[4][t] = fb[1*N_+i];
        xs[5][t] = fb[2*N_+i];
    }
    __syncthreads();
    float w0=Ws[0][t], w1v=Ws[1][t], w2v=Ws[2][t], w3v=Ws[3][t], w4v=Ws[4][t], w5v=Ws[5][t];
    float bias = b2[t];
    bf16* zrow = z2 + (size_t)t*NPOS_ + (size_t)sidx*KNN_;
    float ssum = 0.f, sq = 0.f;
    for (int k0=0;k0<32;k0+=8){
        float y[8];
        #pragma unroll
        for (int u=0;u<8;u++){
            int k = k0+u;
            float acc = bias;
            acc = fmaf(w0, xs[0][k], acc);
            acc = fmaf(w1v,xs[1][k], acc);
            acc = fmaf(w2v,xs[2][k], acc);
            acc = fmaf(w3v,xs[3][k], acc);
            acc = fmaf(w4v,xs[4][k], acc);
            acc = fmaf(w5v,xs[5][k], acc);
            float vr = bits2f(f2bfbits(acc));
            ssum += vr; sq = fmaf(vr, vr, sq);
            y[u] = acc;
        }
        *reinterpret_cast<uint4*>(zrow + k0) = pack8(y);
    }
    const int slot = wid & (NSLOT-1);
    atomicAdd(&part[(size_t)(t*2+0)*NSLOT + slot], ssum);
    atomicAdd(&part[(size_t)(t*2+1)*NSLOT + slot], sq);
}

// -------------------- xm = max over K of relu(a*x+b) (fused BN2) --------------
__global__ __launch_bounds__(256) void xm_kernel(const bf16* __restrict__ z2raw,
                                                 const float2* __restrict__ ab,
                                                 bf16* __restrict__ xm){
    int gid = blockIdx.x*256 + threadIdx.x;
    int c = gid >> 12;
    int bs = gid & 4095;
    float2 s = ab[c];
    const uint4* xp = reinterpret_cast<const uint4*>(z2raw + (size_t)c*NPOS_ + (size_t)bs*KNN_);
    float m = 0.0f;   // relu floor
    #pragma unroll
    for (int r=0;r<4;r++){
        uint4 v = xp[r];
        float fv[8]; unpack8(v, fv);
        #pragma unroll
        for (int u=0;u<8;u++) m = fmaxf(m, fmaf(fv[u], s.x, s.y));
    }
    xm[(size_t)c*4096 + bs] = __float2bfloat16(m);
}

// -------------------- small fp32 GEMM (t3 only) --------------------
__global__ __launch_bounds__(256) void gemm128(const float* __restrict__ A, int lda, int aoff,
                                               const bf16* __restrict__ B,
                                               int M, int N, int K,
                                               float* __restrict__ Cf){
    __shared__ float As[16][128];
    __shared__ float Bs[16][128];
    const int tid = threadIdx.x;
    const int tx = tid & 15, ty = tid >> 4;
    const int m0 = blockIdx.y*128, n0 = blockIdx.x*128;
    float acc[8][8];
    #pragma unroll
    for (int i=0;i<8;i++)
        #pragma unroll
        for (int j=0;j<8;j++) acc[i][j]=0.f;
    const int arow = tid >> 1, akg = tid & 1;
    const int bkk = tid >> 4, bng = tid & 15;
    for (int k0=0;k0<K;k0+=16){
        const float* aptr = A + (size_t)(m0+arow)*lda + aoff + k0 + akg*8;
        float4 a0 = *reinterpret_cast<const float4*>(aptr);
        float4 a1 = *reinterpret_cast<const float4*>(aptr+4);
        As[akg*8+0][arow]=a0.x; As[akg*8+1][arow]=a0.y;
        As[akg*8+2][arow]=a0.z; As[akg*8+3][arow]=a0.w;
        As[akg*8+4][arow]=a1.x; As[akg*8+5][arow]=a1.y;
        As[akg*8+6][arow]=a1.z; As[akg*8+7][arow]=a1.w;
        uint4 bv = *reinterpret_cast<const uint4*>(B + (size_t)(k0+bkk)*N + n0 + bng*8);
        float bf[8]; unpack8(bv, bf);
        *reinterpret_cast<float4*>(&Bs[bkk][bng*8+0]) = make_float4(bf[0],bf[1],bf[2],bf[3]);
        *reinterpret_cast<float4*>(&Bs[bkk][bng*8+4]) = make_float4(bf[4],bf[5],bf[6],bf[7]);
        __syncthreads();
        #pragma unroll
        for (int kk=0;kk<16;kk++){
            float a[8], b[8];
            *reinterpret_cast<float4*>(&a[0]) = *reinterpret_cast<float4*>(&As[kk][ty*8+0]);
            *reinterpret_cast<float4*>(&a[4]) = *reinterpret_cast<float4*>(&As[kk][ty*8+4]);
            *reinterpret_cast<float4*>(&b[0]) = *reinterpret_cast<float4*>(&Bs[kk][tx*8+0]);
            *reinterpret_cast<float4*>(&b[4]) = *reinterpret_cast<float4*>(&Bs[kk][tx*8+4]);
            #pragma unroll
            for (int i=0;i<8;i++)
                #pragma unroll
                for (int j=0;j<8;j++)
                    acc[i][j] = fmaf(a[i], b[j], acc[i][j]);
        }
        __syncthreads();
    }
    const int n = n0 + tx*8;
    #pragma unroll
    for (int i=0;i<8;i++){
        int m = m0 + ty*8 + i;
        *reinterpret_cast<float4*>(Cf + (size_t)m*N + n + 0) = make_float4(acc[i][0],acc[i][1],acc[i][2],acc[i][3]);
        *reinterpret_cast<float4*>(Cf + (size_t)m*N + n + 4) = make_float4(acc[i][4],acc[i][5],acc[i][6],acc[i][7]);
    }
}

// -------------------- MFMA GEMM: LDS-staged bf16 A, fused-BN B, fused stats ---
#define LDK 40
__global__ __launch_bounds__(256) void gemm_mfma(const us* __restrict__ Whi,
                                                 int ldw, int aoff,
                                                 const bf16* __restrict__ act, int K,
                                                 const float2* __restrict__ ab,
                                                 bf16* __restrict__ out,
                                                 const float* __restrict__ t3,
                                                 float* __restrict__ part, int chbase){
    __shared__ __align__(16) us AsH[128*LDK];
    __shared__ __align__(16) us Bs [128*LDK];
    __shared__ float t3s[128][4];
    const us* actu = reinterpret_cast<const us*>(act);
    const int t = threadIdx.x;
    const int m0 = blockIdx.x*128, n0 = blockIdx.y*128;
    const int wave = t>>6, lane = t&63;
    const int wm = wave>>1, wn = wave&1;
    const int q = lane>>4, col = lane&15;

    if (t3 && t < 128){
        const float* src = t3 + (size_t)(m0+t)*4096 + (n0>>5);
        t3s[t][0]=src[0]; t3s[t][1]=src[1]; t3s[t][2]=src[2]; t3s[t][3]=src[3];
    }

    f32x4 acc[4][4];
    #pragma unroll
    for (int i=0;i<4;i++)
        #pragma unroll
        for (int j=0;j<4;j++) acc[i][j] = (f32x4){0.f,0.f,0.f,0.f};

    const int ar = t>>1, ah = t&1;
    const int bn = t&127, bh = t>>7;

    for (int k0=0;k0<K;k0+=32){
        const us* sh = Whi + (size_t)(m0+ar)*ldw + aoff + k0 + ah*16;
        uint4 h0 = *reinterpret_cast<const uint4*>(sh);
        uint4 h1 = *reinterpret_cast<const uint4*>(sh+8);
        *reinterpret_cast<uint4*>(&AsH[ar*LDK + ah*16 + 0]) = h0;
        *reinterpret_cast<uint4*>(&AsH[ar*LDK + ah*16 + 8]) = h1;
        us bvals[16];
        #pragma unroll
        for (int j=0;j<16;j++){
            int k = k0 + bh*16 + j;
            float x = bits2f(actu[(size_t)k*NPOS_ + n0 + bn]);
            float2 s = ab[k];
            bvals[j] = f2bfbits(fmaxf(fmaf(x, s.x, s.y), 0.0f));
        }
        *reinterpret_cast<uint4*>(&Bs[bn*LDK + bh*16 + 0]) = *reinterpret_cast<uint4*>(&bvals[0]);
        *reinterpret_cast<uint4*>(&Bs[bn*LDK + bh*16 + 8]) = *reinterpret_cast<uint4*>(&bvals[8]);
        __syncthreads();
        short8 bf[4], afh[4];
        #pragma unroll
        for (int tn=0;tn<4;tn++)
            bf[tn] = *reinterpret_cast<const short8*>(&Bs[(wn*64+tn*16+col)*LDK + q*8]);
        #pragma unroll
        for (int tm=0;tm<4;tm++)
            afh[tm] = *reinterpret_cast<const short8*>(&AsH[(wm*64+tm*16+col)*LDK + q*8]);
        #pragma unroll
        for (int tm=0;tm<4;tm++)
            #pragma unroll
            for (int tn=0;tn<4;tn++)
                acc[tm][tn] = __builtin_amdgcn_mfma_f32_16x16x32_bf16(afh[tm], bf[tn], acc[tm][tn], 0, 0, 0);
        __syncthreads();
    }
    const int slot = (int)(blockIdx.y & (NSLOT-1));
    #pragma unroll
    for (int tm=0;tm<4;tm++){
        #pragma unroll
        for (int r=0;r<4;r++){
            int m_l = wm*64 + tm*16 + q*4 + r;
            float srow = 0.f, qrow = 0.f;
            #pragma unroll
            for (int tn=0;tn<4;tn++){
                int n_l = wn*64 + tn*16 + col;
                float vv = acc[tm][tn][r];
                if (t3) vv += t3s[m_l][n_l>>5];
                us hb = f2bfbits(vv);
                reinterpret_cast<us*>(out)[(size_t)(m0+m_l)*NPOS_ + n0 + n_l] = hb;
                float vr = bits2f(hb);
                srow += vr; qrow = fmaf(vr, vr, qrow);
            }
            srow = rowsum16(srow);
            qrow = rowsum16(qrow);
            if (col == 15){
                atomicAdd(&part[(size_t)((chbase + m0 + m_l)*2+0)*NSLOT + slot], srow);
                atomicAdd(&part[(size_t)((chbase + m0 + m_l)*2+1)*NSLOT + slot], qrow);
            }
        }
    }
}

// ---- final: fused bn4-coef + BN4 + ReLU + maxpool over K -> out (f32) --------
__global__ __launch_bounds__(256) void final_kernel(const bf16* __restrict__ z4,
                                                    const float* __restrict__ part,
                                                    const float* __restrict__ g4,
                                                    const float* __restrict__ be4,
                                                    float* __restrict__ out){
    __shared__ float abS[2];
    const int t = threadIdx.x;
    const int c = (blockIdx.x >> 2) & 255;
    const int b = blockIdx.x >> 10;
    const int s = ((blockIdx.x & 3) << 8) | t;
    if (t < 64){
        float ss = part[(size_t)((768+c)*2+0)*NSLOT + t];
        float qq = part[(size_t)((768+c)*2+1)*NSLOT + t];
        ss = wave_sum_f32(ss);
        qq = wave_sum_f32(qq);
        if (t==0){
            const float inv = 1.0f/(float)NPOS_;
            float mean = ss*inv;
            float var  = qq*inv - mean*mean;
            float a = g4[c]*rsqrtf(var + BN_EPS_);
            abS[0] = a; abS[1] = be4[c] - mean*a;
        }
    }
    __syncthreads();
    const float a = abS[0], bb = abS[1];
    const int bsi = b*NS_ + s;
    const uint4* zp = reinterpret_cast<const uint4*>(z4 + (size_t)c*NPOS_ + (size_t)bsi*KNN_);
    float m = 0.0f;   // relu floor (relu commutes with max)
    #pragma unroll
    for (int r=0;r<4;r++){
        uint4 v = zp[r];
        float fv[8]; unpack8(v, fv);
        #pragma unroll
        for (int u=0;u<8;u++) m = fmaxf(m, fmaf(fv[u], a, bb));
    }
    out[(size_t)(b*256 + c)*NS_ + s] = m;
}

extern "C" void kernel_launch(void* const* d_in, const int* in_sizes, int n_in,
                              void* d_out, int out_size, void* d_ws, size_t ws_size,
                              hipStream_t stream) {
    const float* p   = (const float*)d_in[0];
    const float* f   = (const float*)d_in[1];
    const float* w1  = (const float*)d_in[2];
    const float* w2  = (const float*)d_in[3];
    const float* b2  = (const float*)d_in[4];
    const float* g2  = (const float*)d_in[5];
    const float* be2 = (const float*)d_in[6];
    const float* w3  = (const float*)d_in[7];
    const float* g3  = (const float*)d_in[8];
    const float* be3 = (const float*)d_in[9];
    const float* w4  = (const float*)d_in[10];
    const float* g4  = (const float*)d_in[11];
    const float* be4 = (const float*)d_in[12];

    // Workspace (~215 MB); z4 aliases z2.
    char* ws = (char*)d_ws;
    float*  W26  = (float*)(ws + 540672);        // 6 KB
    float2* ab2  = (float2*)(ws + 555008);       // 2 KB
    float2* ab3  = (float2*)(ws + 557056);       // 4 KB
    us* whi3 = (us*)(ws + 561152);               // 512 KB
    us* whi4 = (us*)(ws + 1609728);              // 256 KB
    float*  t3   = (float*)(ws + 2134016);       // 8 MB
    bf16*   z2   = (bf16*)(ws + 10522624);       // 64 MB (reused as z4)
    bf16*   xm   = (bf16*)(ws + 77631488);       // 2 MB
    bf16*   z3   = (bf16*)(ws + 79728640);       // 128 MB (end 213946368)
    float*  part = (float*)(ws + 213946368);     // 512 KB partial stats
    int*    prog = (int*)(ws + 214470656);       // 16 KB progress words
    int*    w26flag = (int*)(ws + 214487040);    // 4 B
    bf16*   z4   = z2;

    float* out_cntrd = (float*)d_out;
    float* out_feat  = (float*)d_out + (size_t)B_*NS_*3;

    // 0: zero part + prog + w26flag in one capturable memset
    hipMemsetAsync(ws + 213946368, 0, 540676, stream);
    // 1: FPS producer + preps + convknn consumers
    mega_kernel<<<5637, 256, 0, stream>>>(p, f, out_cntrd, part, prog, w26flag,
                                          w1, w2, W26, b2,
                                          w3, whi3, w4, whi4, z2);
    // 2: BN2 coefficients
    bn_coef<<<1, 256, 0, stream>>>(part, g2, be2, 0, 256, ab2);
    // 3: xm = max_k relu(bn2(z2))
    xm_kernel<<<4096, 256, 0, stream>>>(z2, ab2, xm);
    // 4: t3 = w3[:, :256] @ xm
    gemm128<<<dim3(32,4), 256, 0, stream>>>(w3, 512, 0, xm, 512, 4096, 256, t3);
    // 5: z3 = w3[:, 256:] @ relu(bn2(z2)) + t3   (+ BN3 partial stats)
    gemm_mfma<<<dim3(4,1024), 256, 0, stream>>>(whi3, 512, 256, z2, 256, ab2, z3, t3, part, 256);
    // 6: BN3 coefficients
    bn_coef<<<2, 256, 0, stream>>>(part, g3, be3, 256, 512, ab3);
    // 7: z4 = w4 @ relu(bn3(z3))   (+ BN4 partial stats; z4 aliases z2)
    gemm_mfma<<<dim3(2,1024), 256, 0, stream>>>(whi4, 512, 0, z3, 512, ab3, z4, nullptr, part, 768);
    // 8: fused bn4-coef + BN4 + ReLU + maxpool -> out
    final_kernel<<<4096, 256, 0, stream>>>(z4, part, g4, be4, out_feat);
}